// Round 1
// baseline (1671.431 us; speedup 1.0000x reference)
//
#include <hip/hip_runtime.h>

#define B_ROWS 131072
#define EDIM   256
#define N_E    1024
#define BM     32
#define BN     128
#define KCH    64
#define NT     (N_E / BN)     // 8 n-tiles
#define NKC    (EDIM / KCH)   // 4 k-chunks
#define ZT_STRIDE 260
#define ET_STRIDE 68

#define OUT1 ((size_t)B_ROWS * EDIM)       // loss scalar
#define OUT2 (OUT1 + 1)                    // indices [B]
#define OUT3 (OUT2 + B_ROWS)               // perplexity scalar

// numpy pairwise sum of squares over 128 elements (8-accumulator unrolled,
// exact combine tree), no FMA contraction: matches np.sum(x*x) bit-exactly.
__device__ inline float pw128_sq(const float* p) {
    float r[8];
#pragma unroll
    for (int j = 0; j < 8; ++j) r[j] = __fmul_rn(p[j], p[j]);
    for (int i = 8; i < 128; i += 8) {
#pragma unroll
        for (int j = 0; j < 8; ++j)
            r[j] = __fadd_rn(r[j], __fmul_rn(p[i + j], p[i + j]));
    }
    float s01 = __fadd_rn(r[0], r[1]), s23 = __fadd_rn(r[2], r[3]);
    float s45 = __fadd_rn(r[4], r[5]), s67 = __fadd_rn(r[6], r[7]);
    return __fadd_rn(__fadd_rn(s01, s23), __fadd_rn(s45, s67));
}
__device__ inline float sumsq256(const float* p) {
    return __fadd_rn(pw128_sq(p), pw128_sq(p + 128));  // numpy splits 256 -> 128+128
}

__global__ void vq_esq(const float* __restrict__ emb, float* __restrict__ esq) {
    int n = blockIdx.x * 256 + threadIdx.x;
    if (n < N_E) esq[n] = sumsq256(emb + (size_t)n * EDIM);
}

__global__ __launch_bounds__(256, 2) void vq_main(
    const float* __restrict__ z, const float* __restrict__ emb,
    const float* __restrict__ esq, float* __restrict__ out,
    unsigned int* __restrict__ count, double* __restrict__ lossSum)
{
    __shared__ float zt[BM * ZT_STRIDE];
    __shared__ float et[BN * ET_STRIDE];
    __shared__ float esq_s[N_E];
    __shared__ float zsq_s[BM];
    __shared__ int   rowbest[BM];
    __shared__ double red[256];

    const int tid = threadIdx.x;
    const int blk = blockIdx.x;
    const int ng  = tid & 31;
    const int mg  = tid >> 5;
    const int m0  = mg * 4;

    // ---- stage z tile [32][256] (row stride 260 words) ----
    const float4* zg = (const float4*)(z + (size_t)blk * BM * EDIM);
#pragma unroll
    for (int it = 0; it < 8; ++it) {
        int fidx = it * 256 + tid;
        int m = fidx >> 6, k4 = fidx & 63;
        float4 v = zg[m * 64 + k4];
        *(float4*)&zt[m * ZT_STRIDE + k4 * 4] = v;
    }
    for (int i = tid; i < N_E; i += 256) esq_s[i] = esq[i];
    __syncthreads();

    // ---- zsq per row, numpy-pairwise-exact ----
    if (tid < BM) zsq_s[tid] = sumsq256(&zt[tid * ZT_STRIDE]);

    float bd[4];
    int   bn_[4];
#pragma unroll
    for (int r = 0; r < 4; ++r) { bd[r] = INFINITY; bn_[r] = 0; }

    for (int nt = 0; nt < NT; ++nt) {
        float acc[4][4];
#pragma unroll
        for (int r = 0; r < 4; ++r)
#pragma unroll
            for (int c = 0; c < 4; ++c) acc[r][c] = 0.f;

        for (int kc = 0; kc < NKC; ++kc) {
            __syncthreads();
            // stage e tile [128][64] (row stride 68 words)
#pragma unroll
            for (int it = 0; it < 8; ++it) {
                int fidx = it * 256 + tid;
                int n = fidx >> 4, k4 = fidx & 15;
                const float4* eg = (const float4*)(emb + ((size_t)(nt * BN + n)) * EDIM + kc * KCH);
                float4 v = eg[k4];
                *(float4*)&et[n * ET_STRIDE + k4 * 4] = v;
            }
            __syncthreads();
#pragma unroll
            for (int k4 = 0; k4 < 16; ++k4) {
                float4 zv[4], ev[4];
#pragma unroll
                for (int r = 0; r < 4; ++r)
                    zv[r] = *(const float4*)&zt[(m0 + r) * ZT_STRIDE + kc * KCH + k4 * 4];
#pragma unroll
                for (int c = 0; c < 4; ++c)
                    ev[c] = *(const float4*)&et[(c * 32 + ng) * ET_STRIDE + k4 * 4];
#pragma unroll
                for (int r = 0; r < 4; ++r) {
#pragma unroll
                    for (int c = 0; c < 4; ++c) {
                        acc[r][c] = __fmaf_rn(zv[r].x, ev[c].x, acc[r][c]);
                        acc[r][c] = __fmaf_rn(zv[r].y, ev[c].y, acc[r][c]);
                        acc[r][c] = __fmaf_rn(zv[r].z, ev[c].z, acc[r][c]);
                        acc[r][c] = __fmaf_rn(zv[r].w, ev[c].w, acc[r][c]);
                    }
                }
            }
        }
        // epilogue: d = fl(fl(zsq+esq) - 2*dot), argmin (ascending n, strict <)
#pragma unroll
        for (int r = 0; r < 4; ++r) {
            float zq = zsq_s[m0 + r];
#pragma unroll
            for (int c = 0; c < 4; ++c) {
                int n = nt * BN + c * 32 + ng;
                float d = __fsub_rn(__fadd_rn(zq, esq_s[n]), 2.0f * acc[r][c]);
                if (d < bd[r]) { bd[r] = d; bn_[r] = n; }
            }
        }
    }

    // ---- cross-lane argmin merge (32 lanes per row group), tie -> smaller n ----
#pragma unroll
    for (int r = 0; r < 4; ++r) {
        float d = bd[r];
        int   n = bn_[r];
        for (int msk = 16; msk >= 1; msk >>= 1) {
            float od = __shfl_xor(d, msk, 32);
            int   on = __shfl_xor(n, msk, 32);
            if (od < d || (od == d && on < n)) { d = od; n = on; }
        }
        if (ng == 0) rowbest[m0 + r] = n;
    }
    __syncthreads();

    // ---- output phase: gather z_q, STE, loss partial, index, histogram ----
    const int row = tid >> 3;     // 0..31
    const int q   = tid & 7;      // 8 threads per row
    const size_t grow = (size_t)blk * BM + row;
    const int bn = rowbest[row];
    const float4* ebr = (const float4*)(emb + (size_t)bn * EDIM);
    float4* outr = (float4*)(out + grow * EDIM);
    double lacc = 0.0;
#pragma unroll
    for (int i = 0; i < 8; ++i) {
        int k4 = q + i * 8;
        float4 zv = *(const float4*)&zt[row * ZT_STRIDE + k4 * 4];
        float4 ev = ebr[k4];
        float4 o;
        float s;
        s = __fsub_rn(ev.x, zv.x); o.x = __fadd_rn(zv.x, s); lacc += (double)__fmul_rn(s, s);
        s = __fsub_rn(ev.y, zv.y); o.y = __fadd_rn(zv.y, s); lacc += (double)__fmul_rn(s, s);
        s = __fsub_rn(ev.z, zv.z); o.z = __fadd_rn(zv.z, s); lacc += (double)__fmul_rn(s, s);
        s = __fsub_rn(ev.w, zv.w); o.w = __fadd_rn(zv.w, s); lacc += (double)__fmul_rn(s, s);
        outr[k4] = o;
    }
    if (q == 0) {
        out[OUT2 + grow] = (float)bn;
        atomicAdd(&count[bn], 1u);
    }
    red[tid] = lacc;
    __syncthreads();
    for (int s = 128; s > 0; s >>= 1) {
        if (tid < s) red[tid] += red[tid + s];
        __syncthreads();
    }
    if (tid == 0) atomicAdd(lossSum, red[0]);
}

__global__ void vq_finalize(const unsigned int* __restrict__ count,
                            const double* __restrict__ lossSum,
                            float* __restrict__ out)
{
    __shared__ double red[1024];
    int t = threadIdx.x;
    double em = (double)count[t] * (1.0 / 131072.0);
    red[t] = em * log(em + 1e-10);
    __syncthreads();
    for (int s = 512; s > 0; s >>= 1) {
        if (t < s) red[t] += red[t + s];
        __syncthreads();
    }
    if (t == 0) {
        out[OUT3] = (float)exp(-red[0]);
        double m = lossSum[0] * (1.0 / 33554432.0);   // mean over B*EDIM
        out[OUT1] = (float)(1.25 * m);                 // mean + BETA*mean
    }
}

extern "C" void kernel_launch(void* const* d_in, const int* in_sizes, int n_in,
                              void* d_out, int out_size, void* d_ws, size_t ws_size,
                              hipStream_t stream) {
    const float* z   = (const float*)d_in[0];
    const float* emb = (const float*)d_in[1];
    float* out = (float*)d_out;

    unsigned int* count = (unsigned int*)d_ws;                    // 1024 * 4 B
    double* lossSum     = (double*)((char*)d_ws + 4096);          // 8 B
    float*  esq         = (float*)((char*)d_ws + 4608);           // 1024 * 4 B

    hipMemsetAsync(d_ws, 0, 4104, stream);
    vq_esq<<<4, 256, 0, stream>>>(emb, esq);
    vq_main<<<B_ROWS / BM, 256, 0, stream>>>(z, emb, esq, out, count, lossSum);
    vq_finalize<<<1, 1024, 0, stream>>>(count, lossSum, out);
}